// Round 1
// baseline (31481.473 us; speedup 1.0000x reference)
//
#include <hip/hip_runtime.h>

// ---------------------------------------------------------------------------
// RecurrentEncoderDecoder: persistent-kernel LSTM seq2seq on MI355X (gfx950)
// B=64, H=512, T_enc=256, T_dec=96. One block per CU (256 blocks x 256 thr),
// hand-rolled device-scope grid barrier between recurrence steps.
// MFMA bf16 16x16x32 for all matmuls; fp32 cell state & activations.
// ---------------------------------------------------------------------------

#define BLOCKS 256

typedef short bf16x8 __attribute__((ext_vector_type(8)));
typedef float f32x4  __attribute__((ext_vector_type(4)));
typedef unsigned short u16;

__device__ __forceinline__ f32x4 MFMA16(bf16x8 a, bf16x8 b, f32x4 c) {
  return __builtin_amdgcn_mfma_f32_16x16x32_bf16(a, b, c, 0, 0, 0);
}

__device__ __forceinline__ u16 bfr(float f) {  // fp32 -> bf16 RNE
  unsigned u = __float_as_uint(f);
  u += 0x7FFFu + ((u >> 16) & 1u);
  return (u16)(u >> 16);
}
__device__ __forceinline__ bf16x8 pack8(float4 a, float4 b) {
  bf16x8 r;
  r[0] = (short)bfr(a.x); r[1] = (short)bfr(a.y); r[2] = (short)bfr(a.z); r[3] = (short)bfr(a.w);
  r[4] = (short)bfr(b.x); r[5] = (short)bfr(b.y); r[6] = (short)bfr(b.z); r[7] = (short)bfr(b.w);
  return r;
}
__device__ __forceinline__ bf16x8 loadW8(const float* p) {
  float4 a = *(const float4*)p;
  float4 b = *(const float4*)(p + 4);
  return pack8(a, b);
}
__device__ __forceinline__ float sigm(float x) { return 1.0f / (1.0f + __expf(-x)); }
__device__ __forceinline__ float tanh_f(float x) {
  float a = fabsf(x);
  float e = __expf(-2.0f * a);
  float t = (1.0f - e) / (1.0f + e);
  return x < 0.0f ? -t : t;
}
__device__ __forceinline__ float lstm_h(const float pre[4], float& c) {
  float ig = sigm(pre[0]);
  float fg = sigm(pre[1]);
  float gg = tanh_f(pre[2]);
  float og = sigm(pre[3]);
  c = fg * c + ig * gg;
  return og * tanh_f(c);
}

// ---- workspace layout (byte offsets) ----
static constexpr size_t SZ_SLOT  = (size_t)64 * 512 * 2;          // one [64][512] bf16 slot
static constexpr size_t OFF_OF   = 4096;                          // fw L0 outputs: 257 slots
static constexpr size_t OFF_OBR  = OFF_OF  + 257 * SZ_SLOT;       // bw L0 outputs (time-reversed): 257 slots
static constexpr size_t OFF_H1F  = OFF_OBR + 257 * SZ_SLOT;       // enc L1 fw h ping-pong (2 slots)
static constexpr size_t OFF_H1B  = OFF_H1F + 2 * SZ_SLOT;         // enc L1 bw h ping-pong
static constexpr size_t OFF_DH0  = OFF_H1B + 2 * SZ_SLOT;         // dec L0 h ping-pong
static constexpr size_t OFF_DH1  = OFF_DH0 + 2 * SZ_SLOT;         // dec L1 h ping-pong
static constexpr size_t OFF_SBUF = OFF_DH1 + 2 * SZ_SLOT;         // fp32 [128][2048] merge input (h rows 0..63, c rows 64..127)
static constexpr size_t OFF_CDEC = OFF_SBUF + (size_t)128 * 2048 * 4; // fp32 [2][64][512] decoder init c
static constexpr size_t OFF_Y    = OFF_CDEC + (size_t)2 * 64 * 512 * 4; // fp32 [64] y_prev
static constexpr size_t WS_NEED  = OFF_Y + 256;

__device__ __forceinline__ void gridbar(unsigned* cnt, unsigned* gen, unsigned* sep) {
  __syncthreads();
  if (threadIdx.x == 0) {
    unsigned e = ++(*sep);
    __threadfence();  // release: make this block's writes agent-visible
    unsigned arr = __hip_atomic_fetch_add(cnt, 1u, __ATOMIC_ACQ_REL, __HIP_MEMORY_SCOPE_AGENT) + 1u;
    if (arr == e * (unsigned)BLOCKS) {
      __hip_atomic_store(gen, e, __ATOMIC_RELEASE, __HIP_MEMORY_SCOPE_AGENT);
    } else {
      unsigned g;
      do {
        __builtin_amdgcn_s_sleep(2);
        g = __hip_atomic_load(gen, __ATOMIC_RELAXED, __HIP_MEMORY_SCOPE_AGENT);
      } while (g < e);
    }
  }
  __syncthreads();
  __threadfence();  // acquire: invalidate stale cached lines before reading others' data
}

__global__ __launch_bounds__(256, 1) void red_lstm(
    const float* __restrict__ X,   const float* __restrict__ FUT,
    const float* __restrict__ eWih0,  const float* __restrict__ eWhh0,  const float* __restrict__ eB0,
    const float* __restrict__ eWih0r, const float* __restrict__ eWhh0r, const float* __restrict__ eB0r,
    const float* __restrict__ eWih1,  const float* __restrict__ eWhh1,  const float* __restrict__ eB1,
    const float* __restrict__ eWih1r, const float* __restrict__ eWhh1r, const float* __restrict__ eB1r,
    const float* __restrict__ dWih0,  const float* __restrict__ dWhh0,  const float* __restrict__ dB0,
    const float* __restrict__ dWih1,  const float* __restrict__ dWhh1,  const float* __restrict__ dB1,
    const float* __restrict__ bW,  const float* __restrict__ bB,
    const float* __restrict__ oW,  const float* __restrict__ oB,
    float* __restrict__ OUT, char* __restrict__ ws)
{
  const int blk  = blockIdx.x;
  const int tid  = threadIdx.x;
  const int lane = tid & 63;
  const int wave = tid >> 6;
  const int n16  = lane & 15;   // MFMA: A row (when loading A) / D col (in C/D layout)
  const int quad = lane >> 4;
  const int rowg = wave * 16 + n16;  // global batch row this lane loads for A-frags (M-split waves)
  const int jl   = tid & 3;          // update-thread: hidden-within-block
  const int bb   = tid >> 2;         // update-thread: batch row

  unsigned* bar_cnt = (unsigned*)(ws);
  unsigned* bar_gen = (unsigned*)(ws + 64);
  u16*   OF  = (u16*)(ws + OFF_OF);
  u16*   OBR = (u16*)(ws + OFF_OBR);
  u16*   H1F = (u16*)(ws + OFF_H1F);
  u16*   H1B = (u16*)(ws + OFF_H1B);
  u16*   DH0 = (u16*)(ws + OFF_DH0);
  u16*   DH1 = (u16*)(ws + OFF_DH1);
  float* SB  = (float*)(ws + OFF_SBUF);
  float* CD  = (float*)(ws + OFF_CDEC);
  float* YB  = (float*)(ws + OFF_Y);

  __shared__ float g_s[64 * 20];   // gate pre-acts [batch][16 cols], stride 20 to dodge bank conflicts
  __shared__ unsigned s_ep;
  if (tid == 0) s_ep = 0;
  __syncthreads();

  // =======================================================================
  // ENCODER LAYER 0   (blocks 0..127 = fw, 128..255 = bw; 4 hidden/block)
  // g = X_t @ Wih^T (K=9, fp32 VALU) + h @ Whh^T (K=512, MFMA) + b
  // =======================================================================
  {
    const bool fw = (blk < 128);
    const int  hb = fw ? blk : (blk - 128);
    const int  j0 = hb * 4;
    const int  col = j0 + (n16 & 3) + 512 * (n16 >> 2);  // lane's gate column
    const float* whh = fw ? eWhh0 : eWhh0r;
    const float* wih = fw ? eWih0 : eWih0r;
    const float* bia = fw ? eB0 : eB0r;
    u16* buf = fw ? OF : OBR;   // slot[t] = input state, slot[t+1] = output of step t

    bf16x8 B[16];
    {
      const float* wr = whh + (size_t)col * 512 + quad * 8;
      #pragma unroll
      for (int kk = 0; kk < 16; ++kk) B[kk] = loadW8(wr + kk * 32);
    }
    float wr9[4][9], b4[4];
    #pragma unroll
    for (int g = 0; g < 4; ++g) {
      int cg = j0 + jl + 512 * g;
      b4[g] = bia[cg];
      #pragma unroll
      for (int k = 0; k < 9; ++k) wr9[g][k] = wih[cg * 9 + k];
    }
    float c = 0.0f;

    #pragma unroll 1
    for (int s = 0; s < 256; ++s) {
      const u16* ab = buf + ((size_t)s * 64 + rowg) * 512 + quad * 8;
      f32x4 a0 = {0.f,0.f,0.f,0.f}, a1 = {0.f,0.f,0.f,0.f};
      #pragma unroll
      for (int kk = 0; kk < 16; kk += 2) {
        a0 = MFMA16(*(const bf16x8*)(ab + kk * 32),        B[kk],     a0);
        a1 = MFMA16(*(const bf16x8*)(ab + kk * 32 + 32),   B[kk + 1], a1);
      }
      f32x4 acc = a0 + a1;
      #pragma unroll
      for (int r = 0; r < 4; ++r)
        g_s[(wave * 16 + quad * 4 + r) * 20 + n16] = acc[r];
      __syncthreads();

      const int t = fw ? s : (255 - s);
      float pre[4];
      #pragma unroll
      for (int g = 0; g < 4; ++g) pre[g] = g_s[bb * 20 + jl + 4 * g] + b4[g];
      const float* xp = X + ((size_t)bb * 256 + t) * 9;
      #pragma unroll
      for (int k = 0; k < 9; ++k) {
        float xv = xp[k];
        #pragma unroll
        for (int g = 0; g < 4; ++g) pre[g] += xv * wr9[g][k];
      }
      float h = lstm_h(pre, c);
      buf[((size_t)(s + 1) * 64 + bb) * 512 + j0 + jl] = bfr(h);
      if (s == 255) {  // final states into merge input (fp32)
        int co = fw ? 0 : 512;
        SB[(size_t)bb * 2048 + co + j0 + jl] = h;
        SB[(size_t)(64 + bb) * 2048 + co + j0 + jl] = c;
      }
      gridbar(bar_cnt, bar_gen, &s_ep);
    }
  }

  // =======================================================================
  // ENCODER LAYER 1   K = 512 (own h) + 512 (of_t) + 512 (ob_t); MFMA all
  // =======================================================================
  {
    const bool fw = (blk < 128);
    const int  hb = fw ? blk : (blk - 128);
    const int  j0 = hb * 4;
    const int  col = j0 + (n16 & 3) + 512 * (n16 >> 2);
    const float* whh = fw ? eWhh1 : eWhh1r;
    const float* wih = fw ? eWih1 : eWih1r;
    const float* bia = fw ? eB1 : eB1r;
    u16* hpp = fw ? H1F : H1B;

    bf16x8 B[48];
    {
      const float* wr = whh + (size_t)col * 512 + quad * 8;
      #pragma unroll
      for (int kk = 0; kk < 16; ++kk) B[kk] = loadW8(wr + kk * 32);
      const float* wr2 = wih + (size_t)col * 1024 + quad * 8;
      #pragma unroll
      for (int kk = 0; kk < 32; ++kk) B[16 + kk] = loadW8(wr2 + kk * 32);
    }
    float b4[4];
    #pragma unroll
    for (int g = 0; g < 4; ++g) b4[g] = bia[j0 + jl + 512 * g];
    float c = 0.0f;

    #pragma unroll 1
    for (int s = 0; s < 256; ++s) {
      const int slot_of = fw ? (s + 1)   : (256 - s);  // of output at time tau
      const int slot_ob = fw ? (256 - s) : (s + 1);    // ob output at time tau
      const u16* aH = hpp + ((size_t)(s & 1) * 64 + rowg) * 512 + quad * 8;
      const u16* aF = OF  + ((size_t)slot_of * 64 + rowg) * 512 + quad * 8;
      const u16* aB = OBR + ((size_t)slot_ob * 64 + rowg) * 512 + quad * 8;
      f32x4 a0 = {0.f,0.f,0.f,0.f}, a1 = {0.f,0.f,0.f,0.f};
      #pragma unroll
      for (int kk = 0; kk < 16; kk += 2) {
        a0 = MFMA16(*(const bf16x8*)(aH + kk * 32),      B[kk],     a0);
        a1 = MFMA16(*(const bf16x8*)(aH + kk * 32 + 32), B[kk + 1], a1);
      }
      #pragma unroll
      for (int kk = 0; kk < 16; kk += 2) {
        a0 = MFMA16(*(const bf16x8*)(aF + kk * 32),      B[16 + kk],     a0);
        a1 = MFMA16(*(const bf16x8*)(aF + kk * 32 + 32), B[16 + kk + 1], a1);
      }
      #pragma unroll
      for (int kk = 0; kk < 16; kk += 2) {
        a0 = MFMA16(*(const bf16x8*)(aB + kk * 32),      B[32 + kk],     a0);
        a1 = MFMA16(*(const bf16x8*)(aB + kk * 32 + 32), B[32 + kk + 1], a1);
      }
      f32x4 acc = a0 + a1;
      #pragma unroll
      for (int r = 0; r < 4; ++r)
        g_s[(wave * 16 + quad * 4 + r) * 20 + n16] = acc[r];
      __syncthreads();

      float pre[4];
      #pragma unroll
      for (int g = 0; g < 4; ++g) pre[g] = g_s[bb * 20 + jl + 4 * g] + b4[g];
      float h = lstm_h(pre, c);
      hpp[((size_t)((s & 1) ^ 1) * 64 + bb) * 512 + j0 + jl] = bfr(h);
      if (s == 255) {
        int co = fw ? 1024 : 1536;
        SB[(size_t)bb * 2048 + co + j0 + jl] = h;
        SB[(size_t)(64 + bb) * 2048 + co + j0 + jl] = c;
      }
      gridbar(bar_cnt, bar_gen, &s_ep);
    }
  }

  // =======================================================================
  // MERGE: [h;c](128x2048) @ bidi_w^T (1024x2048) + b, ELU  (fp32 VALU)
  // blocks 0..127: 8 output cols each; thread = (col within 8, row group)
  // =======================================================================
  {
    if (blk < 128) {
      const int colm = blk * 8 + (tid & 7);
      const int rg   = tid >> 3;   // 0..31 -> rows rg*4..rg*4+3
      const float* wrow = bW + (size_t)colm * 2048;
      float am[4];
      #pragma unroll
      for (int r = 0; r < 4; ++r) am[r] = bB[colm];
      #pragma unroll 1
      for (int k = 0; k < 2048; k += 4) {
        float4 w = *(const float4*)(wrow + k);
        #pragma unroll
        for (int r = 0; r < 4; ++r) {
          float4 a = *(const float4*)(SB + (size_t)(rg * 4 + r) * 2048 + k);
          am[r] += a.x * w.x + a.y * w.y + a.z * w.z + a.w * w.w;
        }
      }
      const int l = colm >> 9, j = colm & 511;
      #pragma unroll
      for (int r = 0; r < 4; ++r) {
        int row = rg * 4 + r;
        float v = am[r];
        v = v > 0.f ? v : (__expf(v) - 1.0f);  // ELU
        if (row < 64) {            // h part -> decoder h ping-pong slot 0 (bf16)
          u16* dst = l ? DH1 : DH0;
          dst[(size_t)row * 512 + j] = bfr(v);
        } else {                   // c part -> decoder init c (fp32)
          CD[((size_t)l * 64 + (row - 64)) * 512 + j] = v;
        }
      }
    }
    gridbar(bar_cnt, bar_gen, &s_ep);
  }

  // =======================================================================
  // DECODER: 96 steps x (L0 | L1 | out-proj), 3 sub-barriers per step
  // =======================================================================
  {
    const bool isL0 = (blk < 128);
    const int  hb = isL0 ? blk : (blk - 128);
    const int  j0 = hb * 4;
    const int  col = j0 + (n16 & 3) + 512 * (n16 >> 2);

    bf16x8 BD[32];
    float wr9[4][9], b4[4], c;
    if (isL0) {
      const float* wr = dWhh0 + (size_t)col * 512 + quad * 8;
      #pragma unroll
      for (int kk = 0; kk < 16; ++kk) BD[kk] = loadW8(wr + kk * 32);
      #pragma unroll
      for (int g = 0; g < 4; ++g) {
        int cg = j0 + jl + 512 * g;
        b4[g] = dB0[cg];
        #pragma unroll
        for (int k = 0; k < 9; ++k) wr9[g][k] = dWih0[cg * 9 + k];
      }
      c = CD[(size_t)bb * 512 + j0 + jl];
    } else {
      const float* wr = dWhh1 + (size_t)col * 512 + quad * 8;
      #pragma unroll
      for (int kk = 0; kk < 16; ++kk) BD[kk] = loadW8(wr + kk * 32);
      const float* wr2 = dWih1 + (size_t)col * 512 + quad * 8;
      #pragma unroll
      for (int kk = 0; kk < 16; ++kk) BD[16 + kk] = loadW8(wr2 + kk * 32);
      #pragma unroll
      for (int g = 0; g < 4; ++g) b4[g] = dB1[j0 + jl + 512 * g];
      c = CD[((size_t)64 + bb) * 512 + j0 + jl];
    }
    // output projection weights (block 0 only; lanes n16>=9 hold zeros)
    bf16x8 OBW[16];
    float obv = 0.0f;
    if (blk == 0) {
      if (n16 < 9) {
        const float* wr = oW + (size_t)n16 * 512 + quad * 8;
        #pragma unroll
        for (int kk = 0; kk < 16; ++kk) OBW[kk] = loadW8(wr + kk * 32);
        obv = oB[n16];
      } else {
        #pragma unroll
        for (int kk = 0; kk < 16; ++kk) {
          bf16x8 z = {0,0,0,0,0,0,0,0};
          OBW[kk] = z;
        }
      }
    }

    #pragma unroll 1
    for (int t = 0; t < 96; ++t) {
      // ---- L0 sub-step ----
      if (isL0) {
        const u16* ah = DH0 + ((size_t)(t & 1) * 64 + rowg) * 512 + quad * 8;
        f32x4 a0 = {0.f,0.f,0.f,0.f}, a1 = {0.f,0.f,0.f,0.f};
        #pragma unroll
        for (int kk = 0; kk < 16; kk += 2) {
          a0 = MFMA16(*(const bf16x8*)(ah + kk * 32),      BD[kk],     a0);
          a1 = MFMA16(*(const bf16x8*)(ah + kk * 32 + 32), BD[kk + 1], a1);
        }
        f32x4 acc = a0 + a1;
        #pragma unroll
        for (int r = 0; r < 4; ++r)
          g_s[(wave * 16 + quad * 4 + r) * 20 + n16] = acc[r];
        __syncthreads();
        float pre[4];
        #pragma unroll
        for (int g = 0; g < 4; ++g) pre[g] = g_s[bb * 20 + jl + 4 * g] + b4[g];
        float yp = (t == 0) ? X[((size_t)bb * 256 + 255) * 9] : YB[bb];
        #pragma unroll
        for (int g = 0; g < 4; ++g) pre[g] += yp * wr9[g][0];
        const float* fp = FUT + ((size_t)bb * 96 + t) * 8;
        #pragma unroll
        for (int k = 0; k < 8; ++k) {
          float fv = fp[k];
          #pragma unroll
          for (int g = 0; g < 4; ++g) pre[g] += fv * wr9[g][k + 1];
        }
        float h = lstm_h(pre, c);
        DH0[((size_t)((t & 1) ^ 1) * 64 + bb) * 512 + j0 + jl] = bfr(h);
      }
      gridbar(bar_cnt, bar_gen, &s_ep);

      // ---- L1 sub-step ----
      if (!isL0) {
        const u16* ah = DH1 + ((size_t)(t & 1) * 64 + rowg) * 512 + quad * 8;        // own prev h
        const u16* ax = DH0 + ((size_t)((t & 1) ^ 1) * 64 + rowg) * 512 + quad * 8;  // new h0
        f32x4 a0 = {0.f,0.f,0.f,0.f}, a1 = {0.f,0.f,0.f,0.f};
        #pragma unroll
        for (int kk = 0; kk < 16; kk += 2) {
          a0 = MFMA16(*(const bf16x8*)(ah + kk * 32),      BD[kk],     a0);
          a1 = MFMA16(*(const bf16x8*)(ah + kk * 32 + 32), BD[kk + 1], a1);
        }
        #pragma unroll
        for (int kk = 0; kk < 16; kk += 2) {
          a0 = MFMA16(*(const bf16x8*)(ax + kk * 32),      BD[16 + kk],     a0);
          a1 = MFMA16(*(const bf16x8*)(ax + kk * 32 + 32), BD[16 + kk + 1], a1);
        }
        f32x4 acc = a0 + a1;
        #pragma unroll
        for (int r = 0; r < 4; ++r)
          g_s[(wave * 16 + quad * 4 + r) * 20 + n16] = acc[r];
        __syncthreads();
        float pre[4];
        #pragma unroll
        for (int g = 0; g < 4; ++g) pre[g] = g_s[bb * 20 + jl + 4 * g] + b4[g];
        float h = lstm_h(pre, c);
        DH1[((size_t)((t & 1) ^ 1) * 64 + bb) * 512 + j0 + jl] = bfr(h);
      }
      gridbar(bar_cnt, bar_gen, &s_ep);

      // ---- output projection (block 0): y = h1 @ out_w^T + out_b ----
      if (blk == 0) {
        const u16* ah = DH1 + ((size_t)((t & 1) ^ 1) * 64 + rowg) * 512 + quad * 8;
        f32x4 a0 = {0.f,0.f,0.f,0.f}, a1 = {0.f,0.f,0.f,0.f};
        #pragma unroll
        for (int kk = 0; kk < 16; kk += 2) {
          a0 = MFMA16(*(const bf16x8*)(ah + kk * 32),      OBW[kk],     a0);
          a1 = MFMA16(*(const bf16x8*)(ah + kk * 32 + 32), OBW[kk + 1], a1);
        }
        f32x4 acc = a0 + a1;
        #pragma unroll
        for (int r = 0; r < 4; ++r) {
          int b = wave * 16 + quad * 4 + r;
          float v = acc[r] + obv;
          if (n16 < 9) {
            OUT[(size_t)b * 864 + (size_t)t * 9 + n16] = v;   // (B,96,1,9)
            if (n16 == 0) YB[b] = v;                          // y_prev feedback
          }
        }
      }
      if (t < 95) gridbar(bar_cnt, bar_gen, &s_ep);
    }
  }
}

extern "C" void kernel_launch(void* const* d_in, const int* in_sizes, int n_in,
                              void* d_out, int out_size, void* d_ws, size_t ws_size,
                              hipStream_t stream) {
  (void)in_sizes; (void)n_in; (void)out_size;
  if (ws_size < WS_NEED) return;  // insufficient scratch -> fail loudly (poison output)

  const float* X      = (const float*)d_in[0];
  const float* FUT    = (const float*)d_in[1];
  const float* eWih0  = (const float*)d_in[3];
  const float* eWhh0  = (const float*)d_in[4];
  const float* eB0    = (const float*)d_in[5];
  const float* eWih0r = (const float*)d_in[6];
  const float* eWhh0r = (const float*)d_in[7];
  const float* eB0r   = (const float*)d_in[8];
  const float* eWih1  = (const float*)d_in[9];
  const float* eWhh1  = (const float*)d_in[10];
  const float* eB1    = (const float*)d_in[11];
  const float* eWih1r = (const float*)d_in[12];
  const float* eWhh1r = (const float*)d_in[13];
  const float* eB1r   = (const float*)d_in[14];
  const float* dWih0  = (const float*)d_in[15];
  const float* dWhh0  = (const float*)d_in[16];
  const float* dB0    = (const float*)d_in[17];
  const float* dWih1  = (const float*)d_in[18];
  const float* dWhh1  = (const float*)d_in[19];
  const float* dB1    = (const float*)d_in[20];
  const float* bW     = (const float*)d_in[21];
  const float* bB     = (const float*)d_in[22];
  const float* oW     = (const float*)d_in[23];
  const float* oB     = (const float*)d_in[24];

  char* ws = (char*)d_ws;
  // zero: barrier state + zero-initial-state slots (ws is re-poisoned to 0xAA each call)
  hipMemsetAsync(ws, 0, 4096, stream);                 // barrier cnt/gen
  hipMemsetAsync(ws + OFF_OF, 0, SZ_SLOT, stream);     // enc L0 fw h(-1) = 0
  hipMemsetAsync(ws + OFF_OBR, 0, SZ_SLOT, stream);    // enc L0 bw h(+1) = 0
  hipMemsetAsync(ws + OFF_H1F, 0, SZ_SLOT, stream);    // enc L1 fw h init
  hipMemsetAsync(ws + OFF_H1B, 0, SZ_SLOT, stream);    // enc L1 bw h init

  red_lstm<<<BLOCKS, 256, 0, stream>>>(
      X, FUT,
      eWih0, eWhh0, eB0, eWih0r, eWhh0r, eB0r,
      eWih1, eWhh1, eB1, eWih1r, eWhh1r, eB1r,
      dWih0, dWhh0, dB0, dWih1, dWhh1, dB1,
      bW, bB, oW, oB,
      (float*)d_out, ws);
}

// Round 2
// 4717.579 us; speedup vs baseline: 6.6732x; 6.6732x over previous
//
#include <hip/hip_runtime.h>

// ---------------------------------------------------------------------------
// RecurrentEncoderDecoder: persistent-kernel LSTM seq2seq on MI355X (gfx950)
// B=64, H=512, T_enc=256, T_dec=96. 256 blocks x 256 thr (one per CU).
// R2: fence-free coherence — all cross-block activation traffic uses
// sc0 sc1 (bypass L1+L2, served at Infinity Cache = coherence point);
// grid barrier is flag-gather with relaxed sc0sc1 accesses only. No
// buffer_wbl2 / buffer_inv anywhere in the hot loop.
// ---------------------------------------------------------------------------

#define BLOCKS 256

typedef short bf16x8 __attribute__((ext_vector_type(8)));
typedef float f32x4  __attribute__((ext_vector_type(4)));
typedef unsigned short u16;

__device__ __forceinline__ f32x4 MFMA16(bf16x8 a, bf16x8 b, f32x4 c) {
  return __builtin_amdgcn_mfma_f32_16x16x32_bf16(a, b, c, 0, 0, 0);
}

__device__ __forceinline__ u16 bfr(float f) {  // fp32 -> bf16 RNE
  unsigned u = __float_as_uint(f);
  u += 0x7FFFu + ((u >> 16) & 1u);
  return (u16)(u >> 16);
}
__device__ __forceinline__ bf16x8 pack8(float4 a, float4 b) {
  bf16x8 r;
  r[0] = (short)bfr(a.x); r[1] = (short)bfr(a.y); r[2] = (short)bfr(a.z); r[3] = (short)bfr(a.w);
  r[4] = (short)bfr(b.x); r[5] = (short)bfr(b.y); r[6] = (short)bfr(b.z); r[7] = (short)bfr(b.w);
  return r;
}
__device__ __forceinline__ bf16x8 loadW8(const float* p) {
  float4 a = *(const float4*)p;
  float4 b = *(const float4*)(p + 4);
  return pack8(a, b);
}
__device__ __forceinline__ float sigm(float x) { return 1.0f / (1.0f + __expf(-x)); }
__device__ __forceinline__ float tanh_f(float x) {
  float a = fabsf(x);
  float e = __expf(-2.0f * a);
  float t = (1.0f - e) / (1.0f + e);
  return x < 0.0f ? -t : t;
}
__device__ __forceinline__ float lstm_h(const float pre[4], float& c) {
  float ig = sigm(pre[0]);
  float fg = sigm(pre[1]);
  float gg = tanh_f(pre[2]);
  float og = sigm(pre[3]);
  c = fg * c + ig * gg;
  return og * tanh_f(c);
}

// ---- coherent (IF$-level, L1/L2-bypass) access helpers ----
__device__ __forceinline__ void st_b16_coh(u16* p, u16 v) {
  unsigned uv = v;
  asm volatile("global_store_short %0, %1, off sc0 sc1" :: "v"(p), "v"(uv) : "memory");
}
__device__ __forceinline__ void st_f32_coh(float* p, float v) {
  asm volatile("global_store_dword %0, %1, off sc0 sc1" :: "v"(p), "v"(v) : "memory");
}
__device__ __forceinline__ void st_u32_coh(unsigned* p, unsigned v) {
  asm volatile("global_store_dword %0, %1, off sc0 sc1" :: "v"(p), "v"(v) : "memory");
}
__device__ __forceinline__ float ld_f32_coh(const float* p) {
  float r;
  asm volatile("global_load_dword %0, %1, off sc0 sc1\n\ts_waitcnt vmcnt(0)"
               : "=&v"(r) : "v"(p) : "memory");
  return r;
}
__device__ __forceinline__ unsigned ld_u32_coh(const unsigned* p) {
  unsigned r;
  asm volatile("global_load_dword %0, %1, off sc0 sc1\n\ts_waitcnt vmcnt(0)"
               : "=&v"(r) : "v"(p) : "memory");
  return r;
}
// Load one A-tile (16 bf16x8 frags, 64B stride) coherently; all 16 in flight.
__device__ __forceinline__ void ld_tile_coh(const u16* base, bf16x8 f[16]) {
  asm volatile(
    "global_load_dwordx4 %0, %16, off sc0 sc1\n\t"
    "global_load_dwordx4 %1, %16, off offset:64 sc0 sc1\n\t"
    "global_load_dwordx4 %2, %16, off offset:128 sc0 sc1\n\t"
    "global_load_dwordx4 %3, %16, off offset:192 sc0 sc1\n\t"
    "global_load_dwordx4 %4, %16, off offset:256 sc0 sc1\n\t"
    "global_load_dwordx4 %5, %16, off offset:320 sc0 sc1\n\t"
    "global_load_dwordx4 %6, %16, off offset:384 sc0 sc1\n\t"
    "global_load_dwordx4 %7, %16, off offset:448 sc0 sc1\n\t"
    "global_load_dwordx4 %8, %16, off offset:512 sc0 sc1\n\t"
    "global_load_dwordx4 %9, %16, off offset:576 sc0 sc1\n\t"
    "global_load_dwordx4 %10, %16, off offset:640 sc0 sc1\n\t"
    "global_load_dwordx4 %11, %16, off offset:704 sc0 sc1\n\t"
    "global_load_dwordx4 %12, %16, off offset:768 sc0 sc1\n\t"
    "global_load_dwordx4 %13, %16, off offset:832 sc0 sc1\n\t"
    "global_load_dwordx4 %14, %16, off offset:896 sc0 sc1\n\t"
    "global_load_dwordx4 %15, %16, off offset:960 sc0 sc1\n\t"
    "s_waitcnt vmcnt(0)"
    : "=&v"(f[0]), "=&v"(f[1]), "=&v"(f[2]), "=&v"(f[3]),
      "=&v"(f[4]), "=&v"(f[5]), "=&v"(f[6]), "=&v"(f[7]),
      "=&v"(f[8]), "=&v"(f[9]), "=&v"(f[10]), "=&v"(f[11]),
      "=&v"(f[12]), "=&v"(f[13]), "=&v"(f[14]), "=&v"(f[15])
    : "v"(base)
    : "memory");
}

// ---- workspace layout (byte offsets) ----
static constexpr size_t OFF_GO   = 32768;                         // go word
static constexpr size_t OFF_YF   = 32896;                         // y-ready flag
static constexpr size_t SZ_SLOT  = (size_t)64 * 512 * 2;          // one [64][512] bf16 slot
static constexpr size_t OFF_OF   = 65536;                         // fw L0 outputs: 257 slots
static constexpr size_t OFF_OBR  = OFF_OF  + 257 * SZ_SLOT;       // bw L0 outputs (reversed)
static constexpr size_t OFF_H1F  = OFF_OBR + 257 * SZ_SLOT;       // enc L1 fw h ping-pong
static constexpr size_t OFF_H1B  = OFF_H1F + 2 * SZ_SLOT;
static constexpr size_t OFF_DH0  = OFF_H1B + 2 * SZ_SLOT;         // dec L0 h ping-pong
static constexpr size_t OFF_DH1  = OFF_DH0 + 2 * SZ_SLOT;         // dec L1 h ping-pong
static constexpr size_t OFF_SBUF = OFF_DH1 + 2 * SZ_SLOT;         // fp32 [128][2048]
static constexpr size_t OFF_CDEC = OFF_SBUF + (size_t)128 * 2048 * 4;
static constexpr size_t OFF_Y    = OFF_CDEC + (size_t)2 * 64 * 512 * 4;
static constexpr size_t WS_NEED  = OFF_Y + 256;

// Fence-free grid barrier: arrival flags (1 line/block) + go word, all sc0sc1.
__device__ __forceinline__ void gridbar(char* ws, unsigned e) {
  asm volatile("s_waitcnt vmcnt(0)" ::: "memory");  // drain own data stores to IF$
  __syncthreads();
  unsigned* flags = (unsigned*)ws;
  unsigned* go    = (unsigned*)(ws + OFF_GO);
  const int tid = threadIdx.x;
  if (blockIdx.x == 0) {
    if (tid != 0) {
      const unsigned* fp = flags + (size_t)tid * 32;
      while (ld_u32_coh(fp) < e) {}
    }
    __syncthreads();
    if (tid == 0) st_u32_coh(go, e);
  } else {
    if (tid == 0) {
      st_u32_coh(flags + (size_t)blockIdx.x * 32, e);
      while (ld_u32_coh(go) < e) { __builtin_amdgcn_s_sleep(1); }
    }
    __syncthreads();
  }
}

__global__ __launch_bounds__(256, 1) void red_lstm(
    const float* __restrict__ X,   const float* __restrict__ FUT,
    const float* __restrict__ eWih0,  const float* __restrict__ eWhh0,  const float* __restrict__ eB0,
    const float* __restrict__ eWih0r, const float* __restrict__ eWhh0r, const float* __restrict__ eB0r,
    const float* __restrict__ eWih1,  const float* __restrict__ eWhh1,  const float* __restrict__ eB1,
    const float* __restrict__ eWih1r, const float* __restrict__ eWhh1r, const float* __restrict__ eB1r,
    const float* __restrict__ dWih0,  const float* __restrict__ dWhh0,  const float* __restrict__ dB0,
    const float* __restrict__ dWih1,  const float* __restrict__ dWhh1,  const float* __restrict__ dB1,
    const float* __restrict__ bW,  const float* __restrict__ bB,
    const float* __restrict__ oW,  const float* __restrict__ oB,
    float* __restrict__ OUT, char* __restrict__ ws)
{
  const int blk  = blockIdx.x;
  const int tid  = threadIdx.x;
  const int lane = tid & 63;
  const int wave = tid >> 6;
  const int n16  = lane & 15;
  const int quad = lane >> 4;
  const int rowg = wave * 16 + n16;  // batch row for A-frag loads
  const int jl   = tid & 3;          // update-thread: hidden-within-block
  const int bb   = tid >> 2;         // update-thread: batch row

  u16*   OF  = (u16*)(ws + OFF_OF);
  u16*   OBR = (u16*)(ws + OFF_OBR);
  u16*   H1F = (u16*)(ws + OFF_H1F);
  u16*   H1B = (u16*)(ws + OFF_H1B);
  u16*   DH0 = (u16*)(ws + OFF_DH0);
  u16*   DH1 = (u16*)(ws + OFF_DH1);
  float* SB  = (float*)(ws + OFF_SBUF);
  float* CD  = (float*)(ws + OFF_CDEC);
  float* YB  = (float*)(ws + OFF_Y);
  unsigned* YFLAG = (unsigned*)(ws + OFF_YF);

  __shared__ float g_s[64 * 20];
  unsigned ep = 0;

  // =======================================================================
  // ENCODER LAYER 0   (blocks 0..127 = fw, 128..255 = bw; 4 hidden/block)
  // =======================================================================
  {
    const bool fw = (blk < 128);
    const int  hb = fw ? blk : (blk - 128);
    const int  j0 = hb * 4;
    const int  col = j0 + (n16 & 3) + 512 * (n16 >> 2);
    const float* whh = fw ? eWhh0 : eWhh0r;
    const float* wih = fw ? eWih0 : eWih0r;
    const float* bia = fw ? eB0 : eB0r;
    u16* buf = fw ? OF : OBR;   // slot[t]=input state, slot[t+1]=output of step t

    bf16x8 B[16];
    {
      const float* wr = whh + (size_t)col * 512 + quad * 8;
      #pragma unroll
      for (int kk = 0; kk < 16; ++kk) B[kk] = loadW8(wr + kk * 32);
    }
    float wr9[4][9], b4[4];
    #pragma unroll
    for (int g = 0; g < 4; ++g) {
      int cg = j0 + jl + 512 * g;
      b4[g] = bia[cg];
      #pragma unroll
      for (int k = 0; k < 9; ++k) wr9[g][k] = wih[cg * 9 + k];
    }
    float c = 0.0f;

    #pragma unroll 1
    for (int s = 0; s < 256; ++s) {
      bf16x8 T[16];
      ld_tile_coh(buf + ((size_t)s * 64 + rowg) * 512 + quad * 8, T);
      f32x4 a0 = {0.f,0.f,0.f,0.f}, a1 = {0.f,0.f,0.f,0.f};
      #pragma unroll
      for (int kk = 0; kk < 16; kk += 2) {
        a0 = MFMA16(T[kk],     B[kk],     a0);
        a1 = MFMA16(T[kk + 1], B[kk + 1], a1);
      }
      f32x4 acc = a0 + a1;
      #pragma unroll
      for (int r = 0; r < 4; ++r)
        g_s[(wave * 16 + quad * 4 + r) * 20 + n16] = acc[r];
      __syncthreads();

      const int t = fw ? s : (255 - s);
      float pre[4];
      #pragma unroll
      for (int g = 0; g < 4; ++g) pre[g] = g_s[bb * 20 + jl + 4 * g] + b4[g];
      const float* xp = X + ((size_t)bb * 256 + t) * 9;
      #pragma unroll
      for (int k = 0; k < 9; ++k) {
        float xv = xp[k];
        #pragma unroll
        for (int g = 0; g < 4; ++g) pre[g] += xv * wr9[g][k];
      }
      float h = lstm_h(pre, c);
      st_b16_coh(buf + ((size_t)(s + 1) * 64 + bb) * 512 + j0 + jl, bfr(h));
      if (s == 255) {
        int co = fw ? 0 : 512;
        st_f32_coh(SB + (size_t)bb * 2048 + co + j0 + jl, h);
        st_f32_coh(SB + (size_t)(64 + bb) * 2048 + co + j0 + jl, c);
      }
      gridbar(ws, ++ep);
    }
  }

  // =======================================================================
  // ENCODER LAYER 1   K = 512 (own h) + 512 (of_t) + 512 (ob_t)
  // =======================================================================
  {
    const bool fw = (blk < 128);
    const int  hb = fw ? blk : (blk - 128);
    const int  j0 = hb * 4;
    const int  col = j0 + (n16 & 3) + 512 * (n16 >> 2);
    const float* whh = fw ? eWhh1 : eWhh1r;
    const float* wih = fw ? eWih1 : eWih1r;
    const float* bia = fw ? eB1 : eB1r;
    u16* hpp = fw ? H1F : H1B;

    bf16x8 B[48];
    {
      const float* wr = whh + (size_t)col * 512 + quad * 8;
      #pragma unroll
      for (int kk = 0; kk < 16; ++kk) B[kk] = loadW8(wr + kk * 32);
      const float* wr2 = wih + (size_t)col * 1024 + quad * 8;
      #pragma unroll
      for (int kk = 0; kk < 32; ++kk) B[16 + kk] = loadW8(wr2 + kk * 32);
    }
    float b4[4];
    #pragma unroll
    for (int g = 0; g < 4; ++g) b4[g] = bia[j0 + jl + 512 * g];
    float c = 0.0f;

    #pragma unroll 1
    for (int s = 0; s < 256; ++s) {
      const int slot_of = fw ? (s + 1)   : (256 - s);
      const int slot_ob = fw ? (256 - s) : (s + 1);
      f32x4 a0 = {0.f,0.f,0.f,0.f}, a1 = {0.f,0.f,0.f,0.f};
      {
        bf16x8 T[16];
        ld_tile_coh(hpp + ((size_t)(s & 1) * 64 + rowg) * 512 + quad * 8, T);
        #pragma unroll
        for (int kk = 0; kk < 16; kk += 2) {
          a0 = MFMA16(T[kk],     B[kk],     a0);
          a1 = MFMA16(T[kk + 1], B[kk + 1], a1);
        }
      }
      {
        bf16x8 T[16];
        ld_tile_coh(OF + ((size_t)slot_of * 64 + rowg) * 512 + quad * 8, T);
        #pragma unroll
        for (int kk = 0; kk < 16; kk += 2) {
          a0 = MFMA16(T[kk],     B[16 + kk],     a0);
          a1 = MFMA16(T[kk + 1], B[16 + kk + 1], a1);
        }
      }
      {
        bf16x8 T[16];
        ld_tile_coh(OBR + ((size_t)slot_ob * 64 + rowg) * 512 + quad * 8, T);
        #pragma unroll
        for (int kk = 0; kk < 16; kk += 2) {
          a0 = MFMA16(T[kk],     B[32 + kk],     a0);
          a1 = MFMA16(T[kk + 1], B[32 + kk + 1], a1);
        }
      }
      f32x4 acc = a0 + a1;
      #pragma unroll
      for (int r = 0; r < 4; ++r)
        g_s[(wave * 16 + quad * 4 + r) * 20 + n16] = acc[r];
      __syncthreads();

      float pre[4];
      #pragma unroll
      for (int g = 0; g < 4; ++g) pre[g] = g_s[bb * 20 + jl + 4 * g] + b4[g];
      float h = lstm_h(pre, c);
      st_b16_coh(hpp + ((size_t)((s & 1) ^ 1) * 64 + bb) * 512 + j0 + jl, bfr(h));
      if (s == 255) {
        int co = fw ? 1024 : 1536;
        st_f32_coh(SB + (size_t)bb * 2048 + co + j0 + jl, h);
        st_f32_coh(SB + (size_t)(64 + bb) * 2048 + co + j0 + jl, c);
      }
      gridbar(ws, ++ep);
    }
  }

  // =======================================================================
  // MERGE: [h;c](128x2048) @ bidi_w^T + b, ELU  (fp32 VALU, blocks 0..127)
  // =======================================================================
  {
    if (blk < 128) {
      const int colm = blk * 8 + (tid & 7);
      const int rg   = tid >> 3;
      const float* wrow = bW + (size_t)colm * 2048;
      float am[4];
      #pragma unroll
      for (int r = 0; r < 4; ++r) am[r] = bB[colm];
      #pragma unroll 1
      for (int k = 0; k < 2048; k += 4) {
        float4 w = *(const float4*)(wrow + k);
        #pragma unroll
        for (int r = 0; r < 4; ++r) {
          float4 a = *(const float4*)(SB + (size_t)(rg * 4 + r) * 2048 + k);
          am[r] += a.x * w.x + a.y * w.y + a.z * w.z + a.w * w.w;
        }
      }
      const int l = colm >> 9, j = colm & 511;
      #pragma unroll
      for (int r = 0; r < 4; ++r) {
        int row = rg * 4 + r;
        float v = am[r];
        v = v > 0.f ? v : (__expf(v) - 1.0f);  // ELU
        if (row < 64) {
          u16* dst = l ? DH1 : DH0;
          st_b16_coh(dst + (size_t)row * 512 + j, bfr(v));
        } else {
          st_f32_coh(CD + ((size_t)l * 64 + (row - 64)) * 512 + j, v);
        }
      }
    }
    gridbar(ws, ++ep);
  }

  // =======================================================================
  // DECODER: 96 steps x (A: L0 + [blk128: out-proj y_{t-1}] | B: L1)
  // =======================================================================
  {
    const bool isL0 = (blk < 128);
    const int  hb = isL0 ? blk : (blk - 128);
    const int  j0 = hb * 4;
    const int  col = j0 + (n16 & 3) + 512 * (n16 >> 2);

    bf16x8 BD[32];
    float wr9[4][9], b4[4], c;
    if (isL0) {
      const float* wr = dWhh0 + (size_t)col * 512 + quad * 8;
      #pragma unroll
      for (int kk = 0; kk < 16; ++kk) BD[kk] = loadW8(wr + kk * 32);
      #pragma unroll
      for (int g = 0; g < 4; ++g) {
        int cg = j0 + jl + 512 * g;
        b4[g] = dB0[cg];
        #pragma unroll
        for (int k = 0; k < 9; ++k) wr9[g][k] = dWih0[cg * 9 + k];
      }
      c = CD[(size_t)bb * 512 + j0 + jl];
    } else {
      const float* wr = dWhh1 + (size_t)col * 512 + quad * 8;
      #pragma unroll
      for (int kk = 0; kk < 16; ++kk) BD[kk] = loadW8(wr + kk * 32);
      const float* wr2 = dWih1 + (size_t)col * 512 + quad * 8;
      #pragma unroll
      for (int kk = 0; kk < 16; ++kk) BD[16 + kk] = loadW8(wr2 + kk * 32);
      #pragma unroll
      for (int g = 0; g < 4; ++g) b4[g] = dB1[j0 + jl + 512 * g];
      c = CD[((size_t)64 + bb) * 512 + j0 + jl];
    }
    // out-projection weights live in block 128 (idle during interval A)
    bf16x8 OBW[16];
    float obv = 0.0f;
    if (blk == 128) {
      if (n16 < 9) {
        const float* wr = oW + (size_t)n16 * 512 + quad * 8;
        #pragma unroll
        for (int kk = 0; kk < 16; ++kk) OBW[kk] = loadW8(wr + kk * 32);
        obv = oB[n16];
      } else {
        #pragma unroll
        for (int kk = 0; kk < 16; ++kk) {
          bf16x8 z = {0,0,0,0,0,0,0,0};
          OBW[kk] = z;
        }
      }
    }

    #pragma unroll 1
    for (int t = 0; t < 96; ++t) {
      // ---- interval A: L0 step t; block128 computes y_{t-1} in parallel ----
      if (blk == 128 && t >= 1) {
        bf16x8 T[16];
        ld_tile_coh(DH1 + ((size_t)(t & 1) * 64 + rowg) * 512 + quad * 8, T);
        f32x4 a0 = {0.f,0.f,0.f,0.f}, a1 = {0.f,0.f,0.f,0.f};
        #pragma unroll
        for (int kk = 0; kk < 16; kk += 2) {
          a0 = MFMA16(T[kk],     OBW[kk],     a0);
          a1 = MFMA16(T[kk + 1], OBW[kk + 1], a1);
        }
        f32x4 acc = a0 + a1;
        #pragma unroll
        for (int r = 0; r < 4; ++r) {
          int b = wave * 16 + quad * 4 + r;
          float v = acc[r] + obv;
          if (n16 < 9) {
            OUT[(size_t)b * 864 + (size_t)(t - 1) * 9 + n16] = v;
            if (n16 == 0) st_f32_coh(YB + b, v);
          }
        }
        asm volatile("s_waitcnt vmcnt(0)" ::: "memory");
        __syncthreads();
        if (tid == 0) st_u32_coh(YFLAG, (unsigned)t);
      }
      if (isL0) {
        bf16x8 T[16];
        ld_tile_coh(DH0 + ((size_t)(t & 1) * 64 + rowg) * 512 + quad * 8, T);
        f32x4 a0 = {0.f,0.f,0.f,0.f}, a1 = {0.f,0.f,0.f,0.f};
        #pragma unroll
        for (int kk = 0; kk < 16; kk += 2) {
          a0 = MFMA16(T[kk],     BD[kk],     a0);
          a1 = MFMA16(T[kk + 1], BD[kk + 1], a1);
        }
        f32x4 acc = a0 + a1;
        #pragma unroll
        for (int r = 0; r < 4; ++r)
          g_s[(wave * 16 + quad * 4 + r) * 20 + n16] = acc[r];
        __syncthreads();
        if (t >= 1 && tid == 0) {               // wait for y_{t-1} (overlapped)
          while (ld_u32_coh(YFLAG) < (unsigned)t) {}
        }
        __syncthreads();
        float pre[4];
        #pragma unroll
        for (int g = 0; g < 4; ++g) pre[g] = g_s[bb * 20 + jl + 4 * g] + b4[g];
        float yp = (t == 0) ? X[((size_t)bb * 256 + 255) * 9] : ld_f32_coh(YB + bb);
        #pragma unroll
        for (int g = 0; g < 4; ++g) pre[g] += yp * wr9[g][0];
        const float* fp = FUT + ((size_t)bb * 96 + t) * 8;
        #pragma unroll
        for (int k = 0; k < 8; ++k) {
          float fv = fp[k];
          #pragma unroll
          for (int g = 0; g < 4; ++g) pre[g] += fv * wr9[g][k + 1];
        }
        float h = lstm_h(pre, c);
        st_b16_coh(DH0 + ((size_t)((t & 1) ^ 1) * 64 + bb) * 512 + j0 + jl, bfr(h));
      }
      gridbar(ws, ++ep);

      // ---- interval B: L1 step t ----
      if (!isL0) {
        f32x4 a0 = {0.f,0.f,0.f,0.f}, a1 = {0.f,0.f,0.f,0.f};
        {
          bf16x8 T[16];
          ld_tile_coh(DH1 + ((size_t)(t & 1) * 64 + rowg) * 512 + quad * 8, T);
          #pragma unroll
          for (int kk = 0; kk < 16; kk += 2) {
            a0 = MFMA16(T[kk],     BD[kk],     a0);
            a1 = MFMA16(T[kk + 1], BD[kk + 1], a1);
          }
        }
        {
          bf16x8 T[16];
          ld_tile_coh(DH0 + ((size_t)((t & 1) ^ 1) * 64 + rowg) * 512 + quad * 8, T);
          #pragma unroll
          for (int kk = 0; kk < 16; kk += 2) {
            a0 = MFMA16(T[kk],     BD[16 + kk],     a0);
            a1 = MFMA16(T[kk + 1], BD[16 + kk + 1], a1);
          }
        }
        f32x4 acc = a0 + a1;
        #pragma unroll
        for (int r = 0; r < 4; ++r)
          g_s[(wave * 16 + quad * 4 + r) * 20 + n16] = acc[r];
        __syncthreads();
        float pre[4];
        #pragma unroll
        for (int g = 0; g < 4; ++g) pre[g] = g_s[bb * 20 + jl + 4 * g] + b4[g];
        float h = lstm_h(pre, c);
        st_b16_coh(DH1 + ((size_t)((t & 1) ^ 1) * 64 + bb) * 512 + j0 + jl, bfr(h));
      }
      gridbar(ws, ++ep);
    }

    // final output row t=95 (h1_95 sits in DH1 slot 0)
    if (blk == 128) {
      bf16x8 T[16];
      ld_tile_coh(DH1 + ((size_t)0 * 64 + rowg) * 512 + quad * 8, T);
      f32x4 a0 = {0.f,0.f,0.f,0.f}, a1 = {0.f,0.f,0.f,0.f};
      #pragma unroll
      for (int kk = 0; kk < 16; kk += 2) {
        a0 = MFMA16(T[kk],     OBW[kk],     a0);
        a1 = MFMA16(T[kk + 1], OBW[kk + 1], a1);
      }
      f32x4 acc = a0 + a1;
      #pragma unroll
      for (int r = 0; r < 4; ++r) {
        int b = wave * 16 + quad * 4 + r;
        float v = acc[r] + obv;
        if (n16 < 9) OUT[(size_t)b * 864 + (size_t)95 * 9 + n16] = v;
      }
    }
  }
}

extern "C" void kernel_launch(void* const* d_in, const int* in_sizes, int n_in,
                              void* d_out, int out_size, void* d_ws, size_t ws_size,
                              hipStream_t stream) {
  (void)in_sizes; (void)n_in; (void)out_size;
  if (ws_size < WS_NEED) return;

  const float* X      = (const float*)d_in[0];
  const float* FUT    = (const float*)d_in[1];
  const float* eWih0  = (const float*)d_in[3];
  const float* eWhh0  = (const float*)d_in[4];
  const float* eB0    = (const float*)d_in[5];
  const float* eWih0r = (const float*)d_in[6];
  const float* eWhh0r = (const float*)d_in[7];
  const float* eB0r   = (const float*)d_in[8];
  const float* eWih1  = (const float*)d_in[9];
  const float* eWhh1  = (const float*)d_in[10];
  const float* eB1    = (const float*)d_in[11];
  const float* eWih1r = (const float*)d_in[12];
  const float* eWhh1r = (const float*)d_in[13];
  const float* eB1r   = (const float*)d_in[14];
  const float* dWih0  = (const float*)d_in[15];
  const float* dWhh0  = (const float*)d_in[16];
  const float* dB0    = (const float*)d_in[17];
  const float* dWih1  = (const float*)d_in[18];
  const float* dWhh1  = (const float*)d_in[19];
  const float* dB1    = (const float*)d_in[20];
  const float* bW     = (const float*)d_in[21];
  const float* bB     = (const float*)d_in[22];
  const float* oW     = (const float*)d_in[23];
  const float* oB     = (const float*)d_in[24];

  char* ws = (char*)d_ws;
  hipMemsetAsync(ws, 0, 65536, stream);                // barrier flags + go + yflag
  hipMemsetAsync(ws + OFF_OF, 0, SZ_SLOT, stream);     // enc L0 fw h(-1) = 0
  hipMemsetAsync(ws + OFF_OBR, 0, SZ_SLOT, stream);    // enc L0 bw h(+1) = 0
  hipMemsetAsync(ws + OFF_H1F, 0, SZ_SLOT, stream);    // enc L1 fw h init
  hipMemsetAsync(ws + OFF_H1B, 0, SZ_SLOT, stream);    // enc L1 bw h init

  red_lstm<<<BLOCKS, 256, 0, stream>>>(
      X, FUT,
      eWih0, eWhh0, eB0, eWih0r, eWhh0r, eB0r,
      eWih1, eWhh1, eB1, eWih1r, eWhh1r, eB1r,
      dWih0, dWhh0, dB0, dWih1, dWhh1, dB1,
      bW, bB, oW, oB,
      (float*)d_out, ws);
}